// Round 1
// baseline (1357.242 us; speedup 1.0000x reference)
//
#include <hip/hip_runtime.h>

// Fused 5-layer MLP: 203 -> 175 -> 150 -> 128 -> 80 -> 48, tanh on layers 1-4.
// B = 131072 rows, fp32 in/out. One block = 32 rows, 256 threads.
// Activations ping-pong in LDS (bufA stride 224, bufB stride 192).
// Weights staged per 32-wide k-chunk into the *output* activation buffer
// (dead space until the final barrier), keeping LDS at ~52.8 KB -> 3 blocks/CU.

#define NT 256
#define TM 32
#define KC 32
#define WS 36   // weight LDS row stride in floats (delta 4 banks/lane, 2-way = free)

__device__ __forceinline__ float fast_tanh(float x) {
    // tanh(x) = 1 - 2/(exp(2x)+1); exp via hardware v_exp_f32 (~1e-6 rel err).
    float e = __expf(2.0f * x);
    return 1.0f - 2.0f / (e + 1.0f);
}

// One 32-wide k-chunk of FMAs. sA points at sIn + r0*SIN + k0 (row pair r0,r0+1),
// sW points at weight chunk base + tx*WS. Thread's outputs are j = jj*16 + tx.
template<int JT, int SIN>
__device__ __forceinline__ void chunk_fma(const float* __restrict__ sA,
                                          const float* __restrict__ sW,
                                          float (&acc)[2][JT])
{
#pragma unroll
    for (int kk = 0; kk < KC; kk += 4) {
        const float4 a0 = *(const float4*)(sA + kk);
        const float4 a1 = *(const float4*)(sA + SIN + kk);
#pragma unroll
        for (int jj = 0; jj < JT; ++jj) {
            const float4 w = *(const float4*)(sW + jj * 16 * WS + kk);
            acc[0][jj] = fmaf(a0.x, w.x, acc[0][jj]);
            acc[0][jj] = fmaf(a0.y, w.y, acc[0][jj]);
            acc[0][jj] = fmaf(a0.z, w.z, acc[0][jj]);
            acc[0][jj] = fmaf(a0.w, w.w, acc[0][jj]);
            acc[1][jj] = fmaf(a1.x, w.x, acc[1][jj]);
            acc[1][jj] = fmaf(a1.y, w.y, acc[1][jj]);
            acc[1][jj] = fmaf(a1.z, w.z, acc[1][jj]);
            acc[1][jj] = fmaf(a1.w, w.w, acc[1][jj]);
        }
    }
}

// One layer. sIn: input activations (stride SIN, zero-padded to NCHUNK*KC cols).
// sOW: doubles as weight-staging buffer during the k-loop and output activation
// buffer (stride SOUT) after the final barrier. PADOUT: zero-fill cols
// [FOUT, PADOUT) so the next layer can run full 32-wide chunks safely.
template<int FIN, int FOUT, int SIN, int SOUT, int PADOUT, bool ACT, bool LAST>
__device__ __forceinline__ void layer(const float* __restrict__ W,
                                      const float* __restrict__ bias,
                                      const float* __restrict__ sIn,
                                      float* __restrict__ sOW,
                                      float* __restrict__ gOut,
                                      int row0, int tid)
{
    constexpr int JT = (FOUT + 15) / 16;
    constexpr int NCHUNK = (FIN + KC - 1) / KC;
    const int tx = tid & 15;
    const int ty = tid >> 4;
    const int r0 = ty * 2;

    float acc[2][JT];
#pragma unroll
    for (int jj = 0; jj < JT; ++jj) {
        const int j = jj * 16 + tx;
        const float bv = (j < FOUT) ? bias[j] : 0.0f;
        acc[0][jj] = bv;
        acc[1][jj] = bv;
    }

#pragma unroll 1
    for (int c = 0; c < NCHUNK; ++c) {
        const int k0 = c * KC;
        __syncthreads();   // previous chunk's weight reads (or prev layer) done
        // Stage W[:, k0:k0+KC) -> sOW, zeros beyond FIN. Coalesced along k.
        constexpr int TOT = FOUT * KC;
#pragma unroll
        for (int i = 0; i < (TOT + NT - 1) / NT; ++i) {
            const int idx = i * NT + tid;
            if (idx < TOT) {
                const int j  = idx >> 5;        // KC == 32
                const int kk = idx & (KC - 1);
                const int k  = k0 + kk;
                sOW[j * WS + kk] = (k < FIN) ? W[j * FIN + k] : 0.0f;
            }
        }
        __syncthreads();
        chunk_fma<JT, SIN>(sIn + r0 * SIN + k0, sOW + tx * WS, acc);
    }
    __syncthreads();   // all weight reads done before overwriting sOW w/ outputs

    if constexpr (LAST) {
#pragma unroll
        for (int jj = 0; jj < JT; ++jj) {
            const int j = jj * 16 + tx;
            if (j < FOUT) {
                gOut[(row0 + r0)     * FOUT + j] = acc[0][jj];
                gOut[(row0 + r0 + 1) * FOUT + j] = acc[1][jj];
            }
        }
    } else {
#pragma unroll
        for (int jj = 0; jj < JT; ++jj) {
            const int j = jj * 16 + tx;
            if (j < FOUT) {
                float v0 = acc[0][jj], v1 = acc[1][jj];
                if (ACT) { v0 = fast_tanh(v0); v1 = fast_tanh(v1); }
                sOW[r0       * SOUT + j] = v0;
                sOW[(r0 + 1) * SOUT + j] = v1;
            }
        }
        // zero-pad columns [FOUT, PADOUT) for next layer's full-width chunks
        for (int j = FOUT + tx; j < PADOUT; j += 16) {
            sOW[r0       * SOUT + j] = 0.0f;
            sOW[(r0 + 1) * SOUT + j] = 0.0f;
        }
    }
}

__global__ __launch_bounds__(NT, 3)
void node_embed_mlp(const float* __restrict__ x,
                    const float* __restrict__ W1, const float* __restrict__ b1,
                    const float* __restrict__ W2, const float* __restrict__ b2,
                    const float* __restrict__ W3, const float* __restrict__ b3,
                    const float* __restrict__ W4, const float* __restrict__ b4,
                    const float* __restrict__ W5, const float* __restrict__ b5,
                    float* __restrict__ out)
{
    // bufA: activations w/ stride 224 (L1 in: 203 padded to 7*32=224; L2/L4 out)
    // bufB: activations w/ stride 192 (L1/L3 out) UNION weight staging
    //       (max need: W1 chunk = 175 rows * 36 = 6300 floats)
    __shared__ __align__(16) float bufA[TM * 224];   // 28672 B
    __shared__ __align__(16) float bufB[6336];       // 25344 B  -> total 52.75 KB

    const int tid  = threadIdx.x;
    const int row0 = blockIdx.x * TM;

    // Stage x -> bufA, zero-pad cols [203, 224). Coalesced per row.
    for (int r = 0; r < TM; ++r) {
        for (int k = tid; k < 224; k += NT) {
            bufA[r * 224 + k] = (k < 203) ? x[(row0 + r) * 203 + k] : 0.0f;
        }
    }
    // (barrier at top of layer 1's k-loop covers the staging writes)

    layer<203, 175, 224, 192, 192, true,  false>(W1, b1, bufA, bufB, nullptr, row0, tid);
    layer<175, 150, 192, 224, 160, true,  false>(W2, b2, bufB, bufA, nullptr, row0, tid);
    layer<150, 128, 224, 192, 128, true,  false>(W3, b3, bufA, bufB, nullptr, row0, tid);
    layer<128,  80, 192, 224,  96, true,  false>(W4, b4, bufB, bufA, nullptr, row0, tid);
    layer< 80,  48, 224,   1,   0, false, true >(W5, b5, bufA, bufB, out,     row0, tid);
}

extern "C" void kernel_launch(void* const* d_in, const int* in_sizes, int n_in,
                              void* d_out, int out_size, void* d_ws, size_t ws_size,
                              hipStream_t stream) {
    (void)in_sizes; (void)n_in; (void)d_ws; (void)ws_size; (void)out_size;
    const float* x  = (const float*)d_in[0];
    const float* W1 = (const float*)d_in[1];
    const float* b1 = (const float*)d_in[2];
    const float* W2 = (const float*)d_in[3];
    const float* b2 = (const float*)d_in[4];
    const float* W3 = (const float*)d_in[5];
    const float* b3 = (const float*)d_in[6];
    const float* W4 = (const float*)d_in[7];
    const float* b4 = (const float*)d_in[8];
    const float* W5 = (const float*)d_in[9];
    const float* b5 = (const float*)d_in[10];
    float* out = (float*)d_out;

    const int B = 131072;
    dim3 grid(B / TM), block(NT);
    hipLaunchKernelGGL(node_embed_mlp, grid, block, 0, stream,
                       x, W1, b1, W2, b2, W3, b3, W4, b4, W5, b5, out);
}

// Round 2
// 344.271 us; speedup vs baseline: 3.9424x; 3.9424x over previous
//
#include <hip/hip_runtime.h>

// Fused 5-layer MLP 203->175->150->128->80->48, tanh on 1-4, B=131072, fp32 I/O.
// Strategy: split-bf16 MFMA (v = hi + lo, 3 MFMAs: aH*bH + aL*bH + aH*bL)
// using v_mfma_f32_32x32x16_bf16. Block = 64 rows, 4 waves = 2 row-groups(32) x
// 2 n-split waves. Weights pre-split into d_ws in B-fragment order by a prep
// kernel; staged to LDS with global_load_lds(16B), double-buffered (1 barrier
// per k-chunk). Activations live in LDS as bf16 hi/lo planes (stride 196:
// 2-mod-4 dwords -> 2-way ds_read_b64, free).

typedef short short8 __attribute__((ext_vector_type(8)));
typedef float f32x16 __attribute__((ext_vector_type(16)));
typedef unsigned int uint;
typedef unsigned short ushort;

#define SROW 196            // act plane stride in bf16 elems
#define WBHALF 12288        // one wbuf half: NT_max(6) * 2 planes * 1024 B

// Layer table (K chunks of 16, N tiles of 32), ws pair bases:
// L1: KC=13 NT=6  base 0    (pairs 78)   203->208k, 175->192n
// L2: KC=11 NT=5  base 78   (pairs 55)   175->176k, 150->160n
// L3: KC=10 NT=4  base 133  (pairs 40)   150->160k, 128n
// L4: KC=8  NT=3  base 173  (pairs 24)   128k,      80->96n
// L5: KC=5  NT=2  base 197  (pairs 10)   80k,       48->64n
// total 207 pairs * 2048 B = 423936 B of d_ws

__device__ __forceinline__ ushort f2bf(float f) {
    uint u = __float_as_uint(f);
    u += 0x7FFFu + ((u >> 16) & 1u);        // round-to-nearest-even bf16
    return (ushort)(u >> 16);
}
__device__ __forceinline__ float bf2f(ushort h) { return __uint_as_float(((uint)h) << 16); }
__device__ __forceinline__ float fast_tanh(float x) {
    float e = __expf(2.0f * x);
    return 1.0f - 2.0f / (e + 1.0f);
}
__device__ __forceinline__ void g2l16(const void* g, void* l) {
    __builtin_amdgcn_global_load_lds((const __attribute__((address_space(1))) uint*)g,
                                     (__attribute__((address_space(3))) uint*)l, 16, 0, 0);
}

union U16x8 { uint u[4]; short8 s; };

__device__ __forceinline__ short8 load_a_lds(const ushort* p) {
    U16x8 r;
    *(uint2*)&r.u[0] = *(const uint2*)(p);       // ds_read_b64 (2-way, free)
    *(uint2*)&r.u[2] = *(const uint2*)(p + 4);
    return r.s;
}

// ---------------- prep: split weights into ws in B-fragment order ------------
// B-frag for 32x32x16: lane l holds B[k=(l>>5)*8+j][n=l&31] = W[n0+(l&31)][k0+(l>>5)*8+j]
__global__ void prep_weights(const float* __restrict__ W1, const float* __restrict__ W2,
                             const float* __restrict__ W3, const float* __restrict__ W4,
                             const float* __restrict__ W5, char* __restrict__ ws)
{
    const int b = blockIdx.x, l = threadIdx.x;   // 207 blocks x 64 threads
    int layer, local;
    if      (b <  78) { layer = 0; local = b; }
    else if (b < 133) { layer = 1; local = b - 78; }
    else if (b < 173) { layer = 2; local = b - 133; }
    else if (b < 197) { layer = 3; local = b - 173; }
    else              { layer = 4; local = b - 197; }
    const int NTa[5]  = {6, 5, 4, 3, 2};
    const int FINa[5] = {203, 175, 150, 128, 80};
    const int FOa[5]  = {175, 150, 128, 80, 48};
    const float* Wp = (layer == 0) ? W1 : (layer == 1) ? W2 : (layer == 2) ? W3
                    : (layer == 3) ? W4 : W5;
    const int nt = NTa[layer], fin = FINa[layer], fout = FOa[layer];
    const int c = local / nt, t = local % nt;
    const int n  = t * 32 + (l & 31);
    const int kb = c * 16 + (l >> 5) * 8;
    uint hw[4], lw[4];
#pragma unroll
    for (int j = 0; j < 8; ++j) {
        int k = kb + j;
        float v = (n < fout && k < fin) ? Wp[(size_t)n * fin + k] : 0.0f;  // pads are 0
        ushort hh = f2bf(v);
        ushort ll = f2bf(v - bf2f(hh));
        if (j & 1) { hw[j >> 1] |= ((uint)hh) << 16; lw[j >> 1] |= ((uint)ll) << 16; }
        else       { hw[j >> 1]  = hh;               lw[j >> 1]  = ll; }
    }
    char* dst = ws + (size_t)b * 2048 + l * 16;
    *(uint4*)dst          = make_uint4(hw[0], hw[1], hw[2], hw[3]);  // hi plane
    *(uint4*)(dst + 1024) = make_uint4(lw[0], lw[1], lw[2], lw[3]);  // lo plane
}

// ---------------- main fused MLP --------------------------------------------
template<int KC, int NT, bool ACT, bool LAST, bool FIRST>
__device__ __forceinline__ void run_layer(
    const char* __restrict__ wsL, const float* __restrict__ bias, int FOUT,
    const float* __restrict__ xg,
    const ushort* __restrict__ aHp, const ushort* __restrict__ aLp,
    ushort* __restrict__ oHp, ushort* __restrict__ oLp,
    float* __restrict__ outg,
    char* __restrict__ wbuf, int row0, int tid)
{
    const int l  = tid & 63;
    const int w  = tid >> 6;
    const int rg = w >> 1;        // row-group (32 rows)
    const int ns = w & 1;         // n-split: this wave does tiles t = ns, ns+2, ...
    const int lx = l & 31;
    const int lh = l >> 5;
    constexpr int MT = (NT + 1) / 2;

    f32x16 acc[MT];
#pragma unroll
    for (int m = 0; m < MT; ++m) {
        int t = ns + 2 * m;
        float bv = 0.0f;
        if (t < NT) { int n = t * 32 + lx; bv = (n < FOUT) ? bias[n] : 0.0f; }
#pragma unroll
        for (int r = 0; r < 16; ++r) acc[m][r] = bv;
    }

    __syncthreads();              // prev layer's wbuf reads + D-writes all done
    for (int idx = w; idx < 2 * NT; idx += 4)        // stage chunk 0 -> half 0
        g2l16(wsL + (size_t)((idx >> 1)) * 2048 + (idx & 1) * 1024 + l * 16,
              wbuf + idx * 1024);

#pragma unroll 1
    for (int c = 0; c < KC; ++c) {
        __syncthreads();          // vmcnt(0) drain => chunk c resident; prev mfmas done
        if (c + 1 < KC) {         // prefetch chunk c+1 into the other half
            char* dst = wbuf + ((c + 1) & 1) * WBHALF;
            for (int idx = w; idx < 2 * NT; idx += 4)
                g2l16(wsL + (size_t)((c + 1) * NT + (idx >> 1)) * 2048 + (idx & 1) * 1024 + l * 16,
                      dst + idx * 1024);
        }
        short8 aH, aL;
        if (FIRST) {              // A-frags straight from global x, split inline
            float v[8];
#pragma unroll
            for (int j = 0; j < 8; ++j) {
                int k = c * 16 + lh * 8 + j;
                v[j] = (k < 203) ? xg[(size_t)(rg * 32 + lx) * 203 + k] : 0.0f;
            }
            U16x8 h, lo;
#pragma unroll
            for (int j = 0; j < 8; ++j) {
                ushort hh = f2bf(v[j]);
                ushort ll = f2bf(v[j] - bf2f(hh));
                if (j & 1) { h.u[j >> 1] |= ((uint)hh) << 16; lo.u[j >> 1] |= ((uint)ll) << 16; }
                else       { h.u[j >> 1]  = hh;               lo.u[j >> 1]  = ll; }
            }
            aH = h.s; aL = lo.s;
        } else {                  // A-frags from LDS act planes
            const int off = (rg * 32 + lx) * SROW + c * 16 + lh * 8;
            aH = load_a_lds(aHp + off);
            aL = load_a_lds(aLp + off);
        }
        const char* cb = wbuf + (c & 1) * WBHALF;
#pragma unroll
        for (int m = 0; m < MT; ++m) {
            int t = ns + 2 * m;
            if (t < NT) {
                short8 bH = *(const short8*)(cb + (2 * t) * 1024 + l * 16);
                short8 bL = *(const short8*)(cb + (2 * t + 1) * 1024 + l * 16);
                acc[m] = __builtin_amdgcn_mfma_f32_32x32x16_bf16(aH, bH, acc[m], 0, 0, 0);
                acc[m] = __builtin_amdgcn_mfma_f32_32x32x16_bf16(aL, bH, acc[m], 0, 0, 0);
                acc[m] = __builtin_amdgcn_mfma_f32_32x32x16_bf16(aH, bL, acc[m], 0, 0, 0);
            }
        }
    }
    __syncthreads();              // all A-reads done before D-phase overwrites planes

    // D-phase: C/D layout col=l&31, row=(r&3)+8*(r>>2)+4*(l>>5)  [m74/m101]
#pragma unroll
    for (int m = 0; m < MT; ++m) {
        int t = ns + 2 * m;
        if (t < NT) {
#pragma unroll
            for (int r = 0; r < 16; ++r) {
                float vv = acc[m][r];
                if (ACT) vv = fast_tanh(vv);
                int rowl = rg * 32 + (r & 3) + 8 * (r >> 2) + 4 * lh;
                int col  = t * 32 + lx;
                if (LAST) {
                    if (col < 48)
                        outg[(size_t)(row0 + rowl) * 48 + col] = vv;
                } else {
                    ushort hh = f2bf(vv);
                    ushort ll = f2bf(vv - bf2f(hh));
                    oHp[rowl * SROW + col] = hh;
                    oLp[rowl * SROW + col] = ll;
                }
            }
        }
    }
}

__global__ __launch_bounds__(256, 2)
void mlp_mfma(const float* __restrict__ x,
              const float* __restrict__ b1, const float* __restrict__ b2,
              const float* __restrict__ b3, const float* __restrict__ b4,
              const float* __restrict__ b5,
              const char* __restrict__ ws, float* __restrict__ out)
{
    __shared__ __align__(16) ushort actH[64 * SROW];   // 25088 B
    __shared__ __align__(16) ushort actL[64 * SROW];   // 25088 B
    __shared__ __align__(16) char   wbuf[2 * WBHALF];  // 24576 B  => 74752 B total

    const int tid  = threadIdx.x;
    const int row0 = blockIdx.x * 64;
    const float* xg = x + (size_t)row0 * 203;

    run_layer<13, 6, true,  false, true >(ws,              b1, 175, xg,      nullptr, nullptr, actH, actL, nullptr, wbuf, row0, tid);
    run_layer<11, 5, true,  false, false>(ws +  78 * 2048, b2, 150, nullptr, actH, actL, actH, actL, nullptr, wbuf, row0, tid);
    run_layer<10, 4, true,  false, false>(ws + 133 * 2048, b3, 128, nullptr, actH, actL, actH, actL, nullptr, wbuf, row0, tid);
    run_layer< 8, 3, true,  false, false>(ws + 173 * 2048, b4,  80, nullptr, actH, actL, actH, actL, nullptr, wbuf, row0, tid);
    run_layer< 5, 2, false, true,  false>(ws + 197 * 2048, b5,  48, nullptr, actH, actL, actH, actL, out,     wbuf, row0, tid);
}

extern "C" void kernel_launch(void* const* d_in, const int* in_sizes, int n_in,
                              void* d_out, int out_size, void* d_ws, size_t ws_size,
                              hipStream_t stream) {
    (void)in_sizes; (void)n_in; (void)ws_size; (void)out_size;
    const float* x  = (const float*)d_in[0];
    const float* W1 = (const float*)d_in[1];
    const float* b1 = (const float*)d_in[2];
    const float* W2 = (const float*)d_in[3];
    const float* b2 = (const float*)d_in[4];
    const float* W3 = (const float*)d_in[5];
    const float* b3 = (const float*)d_in[6];
    const float* W4 = (const float*)d_in[7];
    const float* b4 = (const float*)d_in[8];
    const float* W5 = (const float*)d_in[9];
    const float* b5 = (const float*)d_in[10];
    float* out = (float*)d_out;
    char* ws = (char*)d_ws;      // needs 423936 B

    hipLaunchKernelGGL(prep_weights, dim3(207), dim3(64), 0, stream,
                       W1, W2, W3, W4, W5, ws);
    hipLaunchKernelGGL(mlp_mfma, dim3(131072 / 64), dim3(256), 0, stream,
                       x, b1, b2, b3, b4, b5, ws, out);
}

// Round 3
// 298.763 us; speedup vs baseline: 4.5429x; 1.1523x over previous
//
#include <hip/hip_runtime.h>

// Fused 5-layer MLP 203->175->150->128->80->48, tanh on 1-4, B=131072, fp32 I/O.
// Split-bf16 MFMA (v = hi+lo bf16; 3 MFMAs aH*bH + aL*bH + aH*bL), 32x32x16.
// R3: B-fragments read DIRECTLY from global (weights L2-resident, 1 dwordx4 per
// tile-plane, no LDS staging, no K-loop barriers for layers 2-5). Activations in
// ONE packed LDS plane (hi|lo bf16 per dword, stride 180 = bank-period-8 ->
// conflict-free b128). L1 x staged per-chunk through a 5KB LDS buffer with
// coalesced loads + register prefetch. LDS 50 KB -> 3 blocks/CU.

typedef short short8 __attribute__((ext_vector_type(8)));
typedef float f32x16 __attribute__((ext_vector_type(16)));
typedef unsigned int uint;
typedef unsigned short ushort;

#define SROW 180    // actP stride (dwords): mod 32 = 20 -> period-8 full-bank b128
#define XSTR 20     // xst stride (dwords): same good pattern

__device__ __forceinline__ ushort f2bf(float f) {
    uint u = __float_as_uint(f);
    u += 0x7FFFu + ((u >> 16) & 1u);
    return (ushort)(u >> 16);
}
__device__ __forceinline__ float bf2f(ushort h) { return __uint_as_float(((uint)h) << 16); }
__device__ __forceinline__ float fast_tanh(float x) {
    float e = __expf(2.0f * x);
    return 1.0f - 2.0f / (e + 1.0f);
}
__device__ __forceinline__ uint rbf(float v) {   // bf16-RNE rounded bits; hi16 = result>>16
    uint u = __float_as_uint(v);
    return u + 0x7FFFu + ((u >> 16) & 1u);
}

union U4S8 { uint4 u; short8 s; };

// ---------------- prep: split weights into ws in B-fragment order ------------
// (unchanged from R2 — verified correct.) Tile pair p = c*NT + t: 2048 B =
// [hi plane 1024B][lo plane 1024B], lane l holds B[k=(l>>5)*8+j][n=l&31].
__global__ void prep_weights(const float* __restrict__ W1, const float* __restrict__ W2,
                             const float* __restrict__ W3, const float* __restrict__ W4,
                             const float* __restrict__ W5, char* __restrict__ ws)
{
    const int b = blockIdx.x, l = threadIdx.x;   // 207 blocks x 64 threads
    int layer, local;
    if      (b <  78) { layer = 0; local = b; }
    else if (b < 133) { layer = 1; local = b - 78; }
    else if (b < 173) { layer = 2; local = b - 133; }
    else if (b < 197) { layer = 3; local = b - 173; }
    else              { layer = 4; local = b - 197; }
    const int NTa[5]  = {6, 5, 4, 3, 2};
    const int FINa[5] = {203, 175, 150, 128, 80};
    const int FOa[5]  = {175, 150, 128, 80, 48};
    const float* Wp = (layer == 0) ? W1 : (layer == 1) ? W2 : (layer == 2) ? W3
                    : (layer == 3) ? W4 : W5;
    const int nt = NTa[layer], fin = FINa[layer], fout = FOa[layer];
    const int c = local / nt, t = local % nt;
    const int n  = t * 32 + (l & 31);
    const int kb = c * 16 + (l >> 5) * 8;
    uint hw[4], lw[4];
#pragma unroll
    for (int j = 0; j < 8; ++j) {
        int k = kb + j;
        float v = (n < fout && k < fin) ? Wp[(size_t)n * fin + k] : 0.0f;
        ushort hh = f2bf(v);
        ushort ll = f2bf(v - bf2f(hh));
        if (j & 1) { hw[j >> 1] |= ((uint)hh) << 16; lw[j >> 1] |= ((uint)ll) << 16; }
        else       { hw[j >> 1]  = hh;               lw[j >> 1]  = ll; }
    }
    char* dst = ws + (size_t)b * 2048 + l * 16;
    *(uint4*)dst          = make_uint4(hw[0], hw[1], hw[2], hw[3]);
    *(uint4*)(dst + 1024) = make_uint4(lw[0], lw[1], lw[2], lw[3]);
}

// ---------------- D-phase: acc -> tanh -> packed actP (or global out) --------
template<int MT, int NT, int FOUT, int PADN, bool ACT, bool LAST>
__device__ __forceinline__ void d_phase(f32x16* acc, uint* oP, float* outg,
                                        int row0, int rg, int ns, int lx, int lh, int tid)
{
#pragma unroll
    for (int m = 0; m < MT; ++m) {
        int t = ns + 2 * m;
        if (t < NT) {
#pragma unroll
            for (int r = 0; r < 16; ++r) {
                float vv = acc[m][r];
                if (ACT) vv = fast_tanh(vv);
                int rowl = rg * 32 + (r & 3) + 8 * (r >> 2) + 4 * lh;
                int col  = t * 32 + lx;
                if (LAST) {
                    if (col < 48) outg[(size_t)(row0 + rowl) * 48 + col] = vv;
                } else if (col < FOUT) {
                    uint r1  = rbf(vv);
                    uint hib = r1 & 0xFFFF0000u;
                    float lo = vv - __uint_as_float(hib);
                    uint r2  = rbf(lo);
                    oP[rowl * SROW + col] = hib | (r2 >> 16);   // hi in high16, lo in low16
                }
            }
        }
    }
    if (!LAST) {
        if (PADN > 0) {
            for (int idx = tid; idx < 64 * PADN; idx += 256) {
                int row = idx / PADN, p = idx % PADN;
                oP[row * SROW + FOUT + p] = 0u;
            }
        }
        __syncthreads();    // post-D: outputs visible to next layer
    }
}

// ---------------- layers 2-5: A from packed actP, B direct from global -------
template<int KC, int NT, int FOUT, int PADN, bool ACT, bool LAST>
__device__ __forceinline__ void run_layer(const char* __restrict__ wsL,
    const float* __restrict__ bias, const uint* aP, uint* oP, float* outg,
    int row0, int l, int rg, int ns, int lx, int lh, int tid)
{
    constexpr int MT = (NT + 1) / 2;
    f32x16 acc[MT];
#pragma unroll
    for (int m = 0; m < MT; ++m) {
        int t = ns + 2 * m;
        float bv = 0.0f;
        if (t < NT) { int n = t * 32 + lx; bv = (n < FOUT) ? bias[n] : 0.0f; }
#pragma unroll
        for (int r = 0; r < 16; ++r) acc[m][r] = bv;
    }

#pragma unroll
    for (int c = 0; c < KC; ++c) {
        U4S8 bh[MT], bl[MT];
#pragma unroll
        for (int m = 0; m < MT; ++m) {
            int t = ns + 2 * m;
            if (t < NT) {
                const uint4* w = (const uint4*)wsL + (size_t)((c * NT + t) * 2) * 64 + l;
                bh[m].u = w[0];      // hi plane (1024 B = 64 uint4)
                bl[m].u = w[64];     // lo plane
            }
        }
        const uint* ap = aP + (rg * 32 + lx) * SROW + c * 16 + lh * 8;
        uint4 d0 = *(const uint4*)ap;          // ds_read_b128
        uint4 d1 = *(const uint4*)(ap + 4);
        uint dd[8] = {d0.x, d0.y, d0.z, d0.w, d1.x, d1.y, d1.z, d1.w};
        U4S8 ah, al;
        uint* aHu = (uint*)&ah; uint* aLu = (uint*)&al;
#pragma unroll
        for (int j = 0; j < 4; ++j) {
            aHu[j] = (dd[2*j] >> 16)     | (dd[2*j + 1] & 0xFFFF0000u);
            aLu[j] = (dd[2*j] & 0xFFFFu) | (dd[2*j + 1] << 16);
        }
#pragma unroll
        for (int m = 0; m < MT; ++m) {
            int t = ns + 2 * m;
            if (t < NT) {
                acc[m] = __builtin_amdgcn_mfma_f32_32x32x16_bf16(ah.s, bh[m].s, acc[m], 0, 0, 0);
                acc[m] = __builtin_amdgcn_mfma_f32_32x32x16_bf16(al.s, bh[m].s, acc[m], 0, 0, 0);
                acc[m] = __builtin_amdgcn_mfma_f32_32x32x16_bf16(ah.s, bl[m].s, acc[m], 0, 0, 0);
            }
        }
    }
    if (!LAST) __syncthreads();   // pre-D: all actP reads done before overwrite
    d_phase<MT, NT, FOUT, PADN, ACT, LAST>(acc, oP, outg, row0, rg, ns, lx, lh, tid);
}

// ---------------- layer 1: x via small LDS chunk buffer (coalesced) ----------
__device__ __forceinline__ void run_first(const float* __restrict__ x,
    const char* __restrict__ wsL, const float* __restrict__ bias,
    uint* oP, float* xst, int row0, int l, int rg, int ns, int lx, int lh, int tid)
{
    constexpr int KC = 13, NT = 6, MT = 3;
    f32x16 acc[MT];
#pragma unroll
    for (int m = 0; m < MT; ++m) {
        int n = (ns + 2 * m) * 32 + lx;
        float bv = (n < 175) ? bias[n] : 0.0f;
#pragma unroll
        for (int r = 0; r < 16; ++r) acc[m][r] = bv;
    }

    // stage chunk 0 (coalesced: 16-dword runs per row)
#pragma unroll
    for (int i = 0; i < 4; ++i) {
        int e = i * 256 + tid, row = e >> 4, kk = e & 15;
        xst[row * XSTR + kk] = x[(size_t)(row0 + row) * 203 + kk];   // kk < 16 < 203
    }
    __syncthreads();

#pragma unroll
    for (int c = 0; c < KC; ++c) {
        U4S8 bh[MT], bl[MT];
#pragma unroll
        for (int m = 0; m < MT; ++m) {
            const uint4* w = (const uint4*)wsL + (size_t)((c * 6 + ns + 2 * m) * 2) * 64 + l;
            bh[m].u = w[0];
            bl[m].u = w[64];
        }
        float pre[4];
        if (c < 12) {   // register-prefetch next chunk (coalesced global)
#pragma unroll
            for (int i = 0; i < 4; ++i) {
                int e = i * 256 + tid, row = e >> 4, kk = e & 15, k = (c + 1) * 16 + kk;
                pre[i] = (k < 203) ? x[(size_t)(row0 + row) * 203 + k] : 0.0f;
            }
        }
        const float* apf = xst + (rg * 32 + lx) * XSTR + lh * 8;
        float4 v0 = *(const float4*)apf;
        float4 v1 = *(const float4*)(apf + 4);
        float vv[8] = {v0.x, v0.y, v0.z, v0.w, v1.x, v1.y, v1.z, v1.w};
        uint rh[8], rl[8];
#pragma unroll
        for (int j = 0; j < 8; ++j) {
            rh[j] = rbf(vv[j]);
            float lo = vv[j] - __uint_as_float(rh[j] & 0xFFFF0000u);
            rl[j] = rbf(lo);
        }
        U4S8 ah, al;
        uint* aHu = (uint*)&ah; uint* aLu = (uint*)&al;
#pragma unroll
        for (int j = 0; j < 4; ++j) {
            aHu[j] = (rh[2*j] >> 16) | (rh[2*j + 1] & 0xFFFF0000u);
            aLu[j] = (rl[2*j] >> 16) | (rl[2*j + 1] & 0xFFFF0000u);
        }
#pragma unroll
        for (int m = 0; m < MT; ++m) {
            acc[m] = __builtin_amdgcn_mfma_f32_32x32x16_bf16(ah.s, bh[m].s, acc[m], 0, 0, 0);
            acc[m] = __builtin_amdgcn_mfma_f32_32x32x16_bf16(al.s, bh[m].s, acc[m], 0, 0, 0);
            acc[m] = __builtin_amdgcn_mfma_f32_32x32x16_bf16(ah.s, bl[m].s, acc[m], 0, 0, 0);
        }
        if (c < 12) {
            __syncthreads();              // all reads of chunk c done
#pragma unroll
            for (int i = 0; i < 4; ++i) {
                int e = i * 256 + tid, row = e >> 4, kk = e & 15;
                xst[row * XSTR + kk] = pre[i];
            }
            __syncthreads();              // chunk c+1 visible
        }
    }
    // no pre-D barrier: actP untouched so far; d_phase ends with post-D barrier
    d_phase<MT, NT, 175, 1, true, false>(acc, oP, nullptr, row0, rg, ns, lx, lh, tid);
}

__global__ __launch_bounds__(256, 3)
void mlp_mfma(const float* __restrict__ x,
              const float* __restrict__ b1, const float* __restrict__ b2,
              const float* __restrict__ b3, const float* __restrict__ b4,
              const float* __restrict__ b5,
              const char* __restrict__ ws, float* __restrict__ out)
{
    __shared__ __align__(16) uint  actP[64 * SROW];   // 46080 B
    __shared__ __align__(16) float xst[64 * XSTR];    //  5120 B -> 50 KB, 3 blk/CU

    const int tid = threadIdx.x;
    const int l = tid & 63, w = tid >> 6;
    const int rg = w >> 1, ns = w & 1;
    const int lx = l & 31, lh = l >> 5;
    const int row0 = blockIdx.x * 64;

    run_first(x, ws, b1, actP, xst, row0, l, rg, ns, lx, lh, tid);
    run_layer<11, 5, 150, 10, true,  false>(ws +  78 * 2048, b2, actP, actP, nullptr, row0, l, rg, ns, lx, lh, tid);
    run_layer<10, 4, 128,  0, true,  false>(ws + 133 * 2048, b3, actP, actP, nullptr, row0, l, rg, ns, lx, lh, tid);
    run_layer< 8, 3,  80,  0, true,  false>(ws + 173 * 2048, b4, actP, actP, nullptr, row0, l, rg, ns, lx, lh, tid);
    run_layer< 5, 2,  48,  0, false, true >(ws + 197 * 2048, b5, actP, actP, out,     row0, l, rg, ns, lx, lh, tid);
}

extern "C" void kernel_launch(void* const* d_in, const int* in_sizes, int n_in,
                              void* d_out, int out_size, void* d_ws, size_t ws_size,
                              hipStream_t stream) {
    (void)in_sizes; (void)n_in; (void)ws_size; (void)out_size;
    const float* x  = (const float*)d_in[0];
    const float* W1 = (const float*)d_in[1];
    const float* b1 = (const float*)d_in[2];
    const float* W2 = (const float*)d_in[3];
    const float* b2 = (const float*)d_in[4];
    const float* W3 = (const float*)d_in[5];
    const float* b3 = (const float*)d_in[6];
    const float* W4 = (const float*)d_in[7];
    const float* b4 = (const float*)d_in[8];
    const float* W5 = (const float*)d_in[9];
    const float* b5 = (const float*)d_in[10];
    float* out = (float*)d_out;
    char* ws = (char*)d_ws;      // needs 423936 B (verified fits in R2)

    hipLaunchKernelGGL(prep_weights, dim3(207), dim3(64), 0, stream,
                       W1, W2, W3, W4, W5, ws);
    hipLaunchKernelGGL(mlp_mfma, dim3(131072 / 64), dim3(256), 0, stream,
                       x, b1, b2, b3, b4, b5, ws, out);
}